// Round 1
// baseline (784.224 us; speedup 1.0000x reference)
//
#include <hip/hip_runtime.h>
#include <hip/hip_bf16.h>
#include <math.h>

// Fused GNN readout:
//   feat = relu(concat(h,x) @ W1 + b1)   [N,256]
//   feat = relu(feat @ W2 + b2)          [N,64]
//   gf   = segment_sum(feat, batch, G)   [G,64]   (batch sorted)
//   out  = sigmoid(gf @ Wout + bout)     [G]
//
// fp32 throughout (no fp32 MFMA on CDNA4 -> vector FMA kernel).

#define BM   64      // nodes per block
#define BK   8       // K-step for GEMM1 staging
#define H1   256     // layer-1 width
#define H2   64      // layer-2 width
#define F1_LD 260    // feat1 LDS leading dim (256+4, keeps float4 align, breaks bank stride)
#define AS_LD 68     // A-tile LDS leading dim (64+4)
#define W2CH 32      // W2 k-chunk staged per step

#define AS_OFF 0
#define BS_OFF (BK * AS_LD)                    // 544
#define STG_FLOATS (BK * AS_LD + BK * H1)      // 544 + 2048 = 2592 (>= W2CH*H2 = 2048)

__launch_bounds__(256, 2)
__global__ void fused_mlp_pool(const float* __restrict__ h,
                               const float* __restrict__ x,
                               const int*   __restrict__ batch,
                               const float* __restrict__ W1,
                               const float* __restrict__ b1,
                               const float* __restrict__ W2,
                               const float* __restrict__ b2,
                               float* __restrict__ gf,   // [G][H2] accumulators (pre-zeroed)
                               int N, int hid, int emb)
{
    __shared__ float F1s[BM * F1_LD];    // 66560 B
    __shared__ float Stg[STG_FLOATS];    // 10368 B (A/B staging, then W2 chunks)
    __shared__ int   sBatch[BM];

    const int t  = threadIdx.x;
    const int n0 = blockIdx.x * BM;
    const int din = hid + emb;

    // ---- stage batch ids for this block's nodes ----
    if (t < BM) {
        int node = n0 + t;
        sBatch[t] = (node < N) ? batch[node] : -1;
    }

    // ================= GEMM1: [BM,400] x [400,256] =================
    const int tn1 = t & 31;   // 8-col group
    const int tm1 = t >> 5;   // 8-node group

    float acc1[8][8];
    #pragma unroll
    for (int i = 0; i < 8; ++i)
        #pragma unroll
        for (int j = 0; j < 8; ++j) acc1[i][j] = 0.f;

    // A-load mapping: 64 nodes x 8 k per tile, float2 per thread
    const int aNode  = t >> 2;          // 0..63
    const int aK     = (t & 3) * 2;     // 0,2,4,6
    const int gnode  = n0 + aNode;
    const bool aValid = (gnode < N);

    const int nkt = din / BK;           // 50

    // prefetch tile 0 into registers
    float2 avr = make_float2(0.f, 0.f);
    float4 bvr[2];
    {
        if (aValid) {
            int col = aK;  // kbase = 0
            avr = (col < hid) ? *(const float2*)&h[(size_t)gnode * hid + col]
                              : *(const float2*)&x[(size_t)gnode * emb + (col - hid)];
        }
        #pragma unroll
        for (int s = 0; s < 2; ++s) {
            int idx4 = t + 256 * s;
            int row  = idx4 >> 6;
            int col4 = idx4 & 63;
            bvr[s] = *(const float4*)&W1[(size_t)row * H1 + col4 * 4];
        }
    }

    for (int kt = 0; kt < nkt; ++kt) {
        // commit prefetched tile to LDS
        Stg[AS_OFF + aK * AS_LD + aNode]       = avr.x;
        Stg[AS_OFF + (aK + 1) * AS_LD + aNode] = avr.y;
        #pragma unroll
        for (int s = 0; s < 2; ++s) {
            int idx4 = t + 256 * s;
            int row  = idx4 >> 6;
            int col4 = idx4 & 63;
            *(float4*)&Stg[BS_OFF + row * H1 + col4 * 4] = bvr[s];
        }
        __syncthreads();

        // prefetch next tile (global -> regs) while computing this one
        if (kt + 1 < nkt) {
            const int kbase = (kt + 1) * BK;
            avr = make_float2(0.f, 0.f);
            if (aValid) {
                int col = kbase + aK;
                avr = (col < hid) ? *(const float2*)&h[(size_t)gnode * hid + col]
                                  : *(const float2*)&x[(size_t)gnode * emb + (col - hid)];
            }
            #pragma unroll
            for (int s = 0; s < 2; ++s) {
                int idx4 = t + 256 * s;
                int row  = idx4 >> 6;
                int col4 = idx4 & 63;
                bvr[s] = *(const float4*)&W1[(size_t)(kbase + row) * H1 + col4 * 4];
            }
        }

        #pragma unroll
        for (int k = 0; k < BK; ++k) {
            float4 a0  = *(const float4*)&Stg[AS_OFF + k * AS_LD + tm1 * 8];
            float4 a1  = *(const float4*)&Stg[AS_OFF + k * AS_LD + tm1 * 8 + 4];
            float4 b0v = *(const float4*)&Stg[BS_OFF + k * H1 + tn1 * 8];
            float4 b1v = *(const float4*)&Stg[BS_OFF + k * H1 + tn1 * 8 + 4];
            float a[8] = {a0.x, a0.y, a0.z, a0.w, a1.x, a1.y, a1.z, a1.w};
            float b[8] = {b0v.x, b0v.y, b0v.z, b0v.w, b1v.x, b1v.y, b1v.z, b1v.w};
            #pragma unroll
            for (int i = 0; i < 8; ++i)
                #pragma unroll
                for (int j = 0; j < 8; ++j)
                    acc1[i][j] = fmaf(a[i], b[j], acc1[i][j]);
        }
        __syncthreads();
    }

    // ---- bias + relu + store feat1 to LDS ----
    float bias1[8];
    #pragma unroll
    for (int j = 0; j < 8; ++j) bias1[j] = b1[tn1 * 8 + j];
    #pragma unroll
    for (int i = 0; i < 8; ++i) {
        float4 v0, v1;
        v0.x = fmaxf(acc1[i][0] + bias1[0], 0.f);
        v0.y = fmaxf(acc1[i][1] + bias1[1], 0.f);
        v0.z = fmaxf(acc1[i][2] + bias1[2], 0.f);
        v0.w = fmaxf(acc1[i][3] + bias1[3], 0.f);
        v1.x = fmaxf(acc1[i][4] + bias1[4], 0.f);
        v1.y = fmaxf(acc1[i][5] + bias1[5], 0.f);
        v1.z = fmaxf(acc1[i][6] + bias1[6], 0.f);
        v1.w = fmaxf(acc1[i][7] + bias1[7], 0.f);
        *(float4*)&F1s[(tm1 * 8 + i) * F1_LD + tn1 * 8]     = v0;
        *(float4*)&F1s[(tm1 * 8 + i) * F1_LD + tn1 * 8 + 4] = v1;
    }
    __syncthreads();

    // ================= GEMM2: [BM,256] x [256,64] =================
    const int tn2 = t & 15;   // 4-col group
    const int tm2 = t >> 4;   // 4-node group

    float acc2[4][4];
    #pragma unroll
    for (int i = 0; i < 4; ++i)
        #pragma unroll
        for (int j = 0; j < 4; ++j) acc2[i][j] = 0.f;

    for (int kc = 0; kc < H1 / W2CH; ++kc) {
        // stage W2 chunk [W2CH][64] into Stg
        #pragma unroll
        for (int s = 0; s < 8; ++s) {
            int r = (t >> 6) + 4 * s;   // 0..31
            int c = t & 63;
            Stg[r * H2 + c] = W2[(size_t)(kc * W2CH + r) * H2 + c];
        }
        __syncthreads();

        #pragma unroll
        for (int k4 = 0; k4 < W2CH / 4; ++k4) {
            int kk = kc * W2CH + k4 * 4;
            float av[4][4], bv[4][4];
            #pragma unroll
            for (int i = 0; i < 4; ++i) {
                float4 q = *(const float4*)&F1s[(tm2 * 4 + i) * F1_LD + kk];
                av[i][0] = q.x; av[i][1] = q.y; av[i][2] = q.z; av[i][3] = q.w;
            }
            #pragma unroll
            for (int kq = 0; kq < 4; ++kq) {
                float4 q = *(const float4*)&Stg[(k4 * 4 + kq) * H2 + tn2 * 4];
                bv[kq][0] = q.x; bv[kq][1] = q.y; bv[kq][2] = q.z; bv[kq][3] = q.w;
            }
            #pragma unroll
            for (int i = 0; i < 4; ++i)
                #pragma unroll
                for (int j = 0; j < 4; ++j)
                    #pragma unroll
                    for (int kq = 0; kq < 4; ++kq)
                        acc2[i][j] = fmaf(av[i][kq], bv[kq][j], acc2[i][j]);
        }
        __syncthreads();
    }

    // ---- bias + relu + store feat2 (reuse F1s region, [64][68]) ----
    float* F2s = F1s;
    float bias2[4];
    #pragma unroll
    for (int j = 0; j < 4; ++j) bias2[j] = b2[tn2 * 4 + j];
    #pragma unroll
    for (int i = 0; i < 4; ++i) {
        float4 v;
        v.x = fmaxf(acc2[i][0] + bias2[0], 0.f);
        v.y = fmaxf(acc2[i][1] + bias2[1], 0.f);
        v.z = fmaxf(acc2[i][2] + bias2[2], 0.f);
        v.w = fmaxf(acc2[i][3] + bias2[3], 0.f);
        *(float4*)&F2s[(tm2 * 4 + i) * 68 + tn2 * 4] = v;
    }
    __syncthreads();

    // ---- segmented sum over sorted batch ids, one atomic per run ----
    {
        const int c = t & 63;     // column
        const int w = t >> 6;     // 16-node chunk
        const int m0 = w * 16;
        int cur = sBatch[m0];
        float sum = 0.f;
        #pragma unroll
        for (int mm = 0; mm < 16; ++mm) {
            int m = m0 + mm;
            int bb = sBatch[m];
            float v = F2s[m * 68 + c];
            if (bb != cur) {
                if (cur >= 0) atomicAdd(&gf[(size_t)cur * H2 + c], sum);
                sum = 0.f; cur = bb;
            }
            if (bb >= 0) sum += v;
        }
        if (cur >= 0) atomicAdd(&gf[(size_t)cur * H2 + c], sum);
    }
}

// out[g] = sigmoid(dot(gf[g], Wout) + bout)
__global__ void pool_out(const float* __restrict__ gf,
                         const float* __restrict__ Wout,
                         const float* __restrict__ bout,
                         float* __restrict__ out, int G)
{
    const int wid  = threadIdx.x >> 6;
    const int lane = threadIdx.x & 63;
    const int g = blockIdx.x * 4 + wid;
    if (g >= G) return;
    float v = gf[(size_t)g * H2 + lane] * Wout[lane];
    #pragma unroll
    for (int m = 32; m >= 1; m >>= 1) v += __shfl_xor(v, m);
    if (lane == 0) out[g] = 1.f / (1.f + expf(-(v + bout[0])));
}

extern "C" void kernel_launch(void* const* d_in, const int* in_sizes, int n_in,
                              void* d_out, int out_size, void* d_ws, size_t ws_size,
                              hipStream_t stream)
{
    const float* h    = (const float*)d_in[0];
    const float* x    = (const float*)d_in[1];
    const int*   batch= (const int*)d_in[2];
    const float* W1   = (const float*)d_in[3];
    const float* b1   = (const float*)d_in[4];
    const float* W2   = (const float*)d_in[5];
    const float* b2   = (const float*)d_in[6];
    const float* Wout = (const float*)d_in[7];
    const float* bout = (const float*)d_in[8];
    float* out = (float*)d_out;

    const int N   = in_sizes[2];
    const int hid = in_sizes[0] / N;   // 200
    const int emb = in_sizes[1] / N;   // 200
    const int G   = out_size;          // 2048

    float* gf = (float*)d_ws;          // [G][64] accumulators
    hipMemsetAsync(gf, 0, (size_t)G * H2 * sizeof(float), stream);

    const int nb = (N + BM - 1) / BM;
    fused_mlp_pool<<<nb, 256, 0, stream>>>(h, x, batch, W1, b1, W2, b2, gf, N, hid, emb);
    pool_out<<<(G + 3) / 4, 256, 0, stream>>>(gf, Wout, bout, out, G);
}

// Round 2
// 282.534 us; speedup vs baseline: 2.7757x; 2.7757x over previous
//
#include <hip/hip_runtime.h>
#include <math.h>

// Fused GNN readout via bf16x2-split MFMA (v_mfma_f32_32x32x16_bf16):
//   feat1 = relu(concat(h,x) @ W1 + b1)      [N,256]   GEMM1: K=400 (pad 416)
//   feat2 = relu(feat1 @ W2 + b2)            [N,64]    GEMM2: K=256
//   s_n   = feat2 . Wout                      scalar per node
//   out   = sigmoid(segment_sum(s_n) + bout) [G]
// Each fp32 a = ah + al (bf16 RNE split); product uses ah*bh + ah*bl + al*bh
// (dropped al*bl ~ 2^-18 relative — far inside the 2e-2 |dz| budget).

typedef __attribute__((ext_vector_type(8)))  short short8v;
typedef __attribute__((ext_vector_type(16))) float f32x16;

#define G_NUM 2048
#define HID 200
#define EMB 200
#define DIN 400
#define NH1 256
#define NH2 64
#define BM  64
#define NKS1 26        // bf16 K-steps (of 16) for GEMM1, K padded 400->416
#define NCHUNK 13      // 32-fp32-col staging chunks
#define NKS2 16        // K-steps for GEMM2 (K=256)
#define AKS 40         // A-stage LDS row stride in bf16 (80B: 16B-aligned, 2-way banks max)

#define W1P_SH8 (NKS1*8*64)   // 13312 fragments (16B each) per plane
#define W2P_SH8 (NKS2*2*64)   // 2048

__device__ __forceinline__ unsigned short f2bf(float f) {
    union { float f; unsigned u; } v; v.f = f;
    unsigned r = v.u + 0x7fffu + ((v.u >> 16) & 1u);   // RNE
    return (unsigned short)(r >> 16);
}
__device__ __forceinline__ float bf2f(unsigned short b) {
    union { unsigned u; float f; } v; v.u = ((unsigned)b) << 16;
    return v.f;
}

// Pre-pack W1/W2 into MFMA-fragment order, hi/lo bf16 planes.
// Fragment (ks, ntile, lane) holds 8 bf16: B[k0+j][col], k0=ks*16+(lane>>5)*8,
// col=ntile*32+(lane&31). Contiguous-8 k in BOTH A and B => any consistent
// hw k-permutation cancels in the dot product.
__global__ void pack_weights(const float* __restrict__ W1, const float* __restrict__ W2,
                             unsigned short* __restrict__ w1h, unsigned short* __restrict__ w1l,
                             unsigned short* __restrict__ w2h, unsigned short* __restrict__ w2l)
{
    int idx = blockIdx.x * 256 + threadIdx.x;
    if (idx < W1P_SH8) {
        int l  = idx & 63;
        int nt = (idx >> 6) & 7;
        int ks = idx >> 9;
        int col = nt * 32 + (l & 31);
        int k0  = ks * 16 + (l >> 5) * 8;
        short8v H, L;
        #pragma unroll
        for (int j = 0; j < 8; ++j) {
            int k = k0 + j;
            float v = (k < DIN) ? W1[(size_t)k * NH1 + col] : 0.f;
            unsigned short hh = f2bf(v);
            H[j] = (short)hh;
            L[j] = (short)f2bf(v - bf2f(hh));
        }
        ((short8v*)w1h)[idx] = H;
        ((short8v*)w1l)[idx] = L;
    } else if (idx < W1P_SH8 + W2P_SH8) {
        int i2 = idx - W1P_SH8;
        int l  = i2 & 63;
        int nt = (i2 >> 6) & 1;
        int ks = i2 >> 7;
        int col = nt * 32 + (l & 31);
        int k0  = ks * 16 + (l >> 5) * 8;
        short8v H, L;
        #pragma unroll
        for (int j = 0; j < 8; ++j) {
            float v = W2[(size_t)(k0 + j) * NH2 + col];
            unsigned short hh = f2bf(v);
            H[j] = (short)hh;
            L[j] = (short)f2bf(v - bf2f(hh));
        }
        ((short8v*)w2h)[i2] = H;
        ((short8v*)w2l)[i2] = L;
    }
}

__launch_bounds__(256, 2)
__global__ void fused_readout(const float* __restrict__ h, const float* __restrict__ x,
                              const int* __restrict__ batch,
                              const unsigned short* __restrict__ w1h, const unsigned short* __restrict__ w1l,
                              const unsigned short* __restrict__ w2h, const unsigned short* __restrict__ w2l,
                              const float* __restrict__ b1, const float* __restrict__ b2,
                              const float* __restrict__ Wout,
                              float* __restrict__ gf1d, int N)
{
    // 65536 B LDS, time-multiplexed:
    //   [phase GEMM1] Ast: 2 bufs x 2 planes x [64][AKS] bf16 = 20480 B at offset 0
    //   [phase GEMM2] F1h [64][256] at 0, F1l at 32768 B (XOR-8-block swizzled cols)
    //   [phase pool ] s2p[2][64] f32 at 0, srow[64] f32 at 512 B
    __shared__ __align__(16) unsigned short lds[32768];
    unsigned short* Ast = lds;
    unsigned short* F1h = lds;
    unsigned short* F1l = lds + 64 * 256;
    float* s2p  = (float*)lds;          // 128 floats
    float* srow = (float*)(lds + 256);  // 64 floats (byte 512)

    const int t    = threadIdx.x;
    const int lane = t & 63;
    const int w    = t >> 6;
    const int n0   = blockIdx.x * BM;
    const int l31  = lane & 31;
    const int hs   = lane >> 5;         // k-half select

    // staging mapping: 4 threads per node row, 8 fp32 cols each
    const int  sRow   = t >> 2;
    const int  sK     = (t & 3) * 8;
    const int  gnode  = n0 + sRow;
    const bool rowOk  = (gnode < N);
    const float* hrow = h + (size_t)gnode * HID;
    const float* xrow = x + (size_t)gnode * EMB;

    f32x16 acc00, acc01, acc10, acc11;
    #pragma unroll
    for (int r = 0; r < 16; ++r) { acc00[r] = 0.f; acc01[r] = 0.f; acc10[r] = 0.f; acc11[r] = 0.f; }

    // ---- stage chunk 0 (cols 0..31, all from h) ----
    {
        float4 ga = make_float4(0,0,0,0), gb = make_float4(0,0,0,0);
        if (rowOk) { ga = *(const float4*)&hrow[sK]; gb = *(const float4*)&hrow[sK + 4]; }
        float vv[8] = {ga.x,ga.y,ga.z,ga.w,gb.x,gb.y,gb.z,gb.w};
        short8v H, L;
        #pragma unroll
        for (int j = 0; j < 8; ++j) {
            unsigned short hh = f2bf(vv[j]);
            H[j] = (short)hh; L[j] = (short)f2bf(vv[j] - bf2f(hh));
        }
        *(short8v*)&Ast[(0*64 + sRow)*AKS + sK] = H;   // buf0 plane hi
        *(short8v*)&Ast[(1*64 + sRow)*AKS + sK] = L;   // buf0 plane lo
    }
    __syncthreads();

    // ================= GEMM1 =================
    for (int c = 0; c < NCHUNK; ++c) {
        const int  buf     = c & 1;
        const bool hasNext = (c + 1 < NCHUNK);

        // 1) next-chunk global A loads (early issue; latency hidden under MFMAs)
        float4 ga = make_float4(0,0,0,0), gb = make_float4(0,0,0,0);
        if (hasNext && rowOk) {
            int col0 = (c + 1) * 32 + sK;
            if (col0 + 8 <= HID)      { ga = *(const float4*)&hrow[col0];       gb = *(const float4*)&hrow[col0 + 4]; }
            else if (col0 < DIN)      { ga = *(const float4*)&xrow[col0 - HID]; gb = *(const float4*)&xrow[col0 - HID + 4]; }
        }

        // 2) B fragments for both K-steps of this chunk (global, L2-resident pack)
        short8v bh[2][2], bl[2][2];  // [s][ntile]
        #pragma unroll
        for (int s = 0; s < 2; ++s) {
            size_t base = (size_t)((2*c + s) * 8 + w * 2) * 64 + lane;
            bh[s][0] = ((const short8v*)w1h)[base];
            bh[s][1] = ((const short8v*)w1h)[base + 64];
            bl[s][0] = ((const short8v*)w1l)[base];
            bl[s][1] = ((const short8v*)w1l)[base + 64];
        }

        // 3) A fragments (LDS)
        short8v ah[2][2], al[2][2];  // [s][mtile]
        #pragma unroll
        for (int s = 0; s < 2; ++s)
            #pragma unroll
            for (int mi = 0; mi < 2; ++mi) {
                int row = mi * 32 + l31;
                int off = ((buf*2 + 0)*64 + row)*AKS + s*16 + hs*8;
                ah[s][mi] = *(const short8v*)&Ast[off];
                al[s][mi] = *(const short8v*)&Ast[off + 64*AKS];
            }

        // 4) 24 MFMAs
        #pragma unroll
        for (int s = 0; s < 2; ++s) {
            acc00 = __builtin_amdgcn_mfma_f32_32x32x16_bf16(ah[s][0], bh[s][0], acc00, 0,0,0);
            acc00 = __builtin_amdgcn_mfma_f32_32x32x16_bf16(ah[s][0], bl[s][0], acc00, 0,0,0);
            acc00 = __builtin_amdgcn_mfma_f32_32x32x16_bf16(al[s][0], bh[s][0], acc00, 0,0,0);
            acc01 = __builtin_amdgcn_mfma_f32_32x32x16_bf16(ah[s][0], bh[s][1], acc01, 0,0,0);
            acc01 = __builtin_amdgcn_mfma_f32_32x32x16_bf16(ah[s][0], bl[s][1], acc01, 0,0,0);
            acc01 = __builtin_amdgcn_mfma_f32_32x32x16_bf16(al[s][0], bh[s][1], acc01, 0,0,0);
            acc10 = __builtin_amdgcn_mfma_f32_32x32x16_bf16(ah[s][1], bh[s][0], acc10, 0,0,0);
            acc10 = __builtin_amdgcn_mfma_f32_32x32x16_bf16(ah[s][1], bl[s][0], acc10, 0,0,0);
            acc10 = __builtin_amdgcn_mfma_f32_32x32x16_bf16(al[s][1], bh[s][0], acc10, 0,0,0);
            acc11 = __builtin_amdgcn_mfma_f32_32x32x16_bf16(ah[s][1], bh[s][1], acc11, 0,0,0);
            acc11 = __builtin_amdgcn_mfma_f32_32x32x16_bf16(ah[s][1], bl[s][1], acc11, 0,0,0);
            acc11 = __builtin_amdgcn_mfma_f32_32x32x16_bf16(al[s][1], bh[s][1], acc11, 0,0,0);
        }

        // 5) convert + stage next chunk into the other buffer
        if (hasNext) {
            float vv[8] = {ga.x,ga.y,ga.z,ga.w,gb.x,gb.y,gb.z,gb.w};
            short8v H, L;
            #pragma unroll
            for (int j = 0; j < 8; ++j) {
                unsigned short hh = f2bf(vv[j]);
                H[j] = (short)hh; L[j] = (short)f2bf(vv[j] - bf2f(hh));
            }
            int nb = buf ^ 1;
            *(short8v*)&Ast[((nb*2 + 0)*64 + sRow)*AKS + sK] = H;
            *(short8v*)&Ast[((nb*2 + 1)*64 + sRow)*AKS + sK] = L;
        }
        __syncthreads();
    }

    // ---- epilogue1: bias + relu + bf16x2 split -> F1 (XOR-swizzled, overlaps Ast) ----
    // C/D layout (m74/m101): col = lane&31, row = (r&3) + 8*(r>>2) + 4*(lane>>5)
    const float b1c0 = b1[w*64 + l31];
    const float b1c1 = b1[w*64 + 32 + l31];
#define EPI1(ACC, MI, NI) do {                                            \
        int gcol = w*64 + (NI)*32 + l31;                                  \
        float bb = (NI) ? b1c1 : b1c0;                                    \
        _Pragma("unroll")                                                 \
        for (int r = 0; r < 16; ++r) {                                    \
            int grow = (MI)*32 + (r & 3) + 8*(r >> 2) + 4*hs;             \
            float v = fmaxf(ACC[r] + bb, 0.f);                            \
            unsigned short hh = f2bf(v);                                  \
            int phys = grow*256 + (((gcol >> 3) ^ (grow & 31)) << 3) + (gcol & 7); \
            F1h[phys] = hh;                                               \
            F1l[phys] = f2bf(v - bf2f(hh));                               \
        } } while (0)
    EPI1(acc00, 0, 0); EPI1(acc01, 0, 1); EPI1(acc10, 1, 0); EPI1(acc11, 1, 1);
#undef EPI1
    __syncthreads();

    // ================= GEMM2: feat2 = relu(feat1 @ W2 + b2) =================
    f32x16 acc2;
    #pragma unroll
    for (int r = 0; r < 16; ++r) acc2[r] = 0.f;
    const int m2  = w >> 1;       // node-row half
    const int nt2 = w & 1;        // col half
    const int arow = m2*32 + l31;

    short8v bhc = ((const short8v*)w2h)[(size_t)nt2*64 + lane];
    short8v blc = ((const short8v*)w2l)[(size_t)nt2*64 + lane];
    #pragma unroll
    for (int ks = 0; ks < NKS2; ++ks) {
        short8v bhn = bhc, bln = blc;
        if (ks + 1 < NKS2) {
            size_t nbase = (size_t)((ks + 1)*2 + nt2)*64 + lane;
            bhn = ((const short8v*)w2h)[nbase];
            bln = ((const short8v*)w2l)[nbase];
        }
        int blk  = (ks*2 + hs) ^ (arow & 31);
        int aoff = arow*256 + blk*8;
        short8v ah2 = *(const short8v*)&F1h[aoff];
        short8v al2 = *(const short8v*)&F1l[aoff];
        acc2 = __builtin_amdgcn_mfma_f32_32x32x16_bf16(ah2, bhc, acc2, 0,0,0);
        acc2 = __builtin_amdgcn_mfma_f32_32x32x16_bf16(ah2, blc, acc2, 0,0,0);
        acc2 = __builtin_amdgcn_mfma_f32_32x32x16_bf16(al2, bhc, acc2, 0,0,0);
        bhc = bhn; blc = bln;
    }
    __syncthreads();   // all F1 reads done; s2p/srow may now overwrite LDS

    // ---- epilogue2: s_n = relu(feat2 + b2) . Wout, 32-col shfl reduce ----
    {
        const int   col2 = nt2*32 + l31;
        const float b2c  = b2[col2];
        const float woc  = Wout[col2];
        #pragma unroll
        for (int r = 0; r < 16; ++r) {
            float v = fmaxf(acc2[r] + b2c, 0.f) * woc;
            v += __shfl_xor(v, 1);
            v += __shfl_xor(v, 2);
            v += __shfl_xor(v, 4);
            v += __shfl_xor(v, 8);
            v += __shfl_xor(v, 16);
            if (l31 == 0) {
                int grow = m2*32 + (r & 3) + 8*(r >> 2) + 4*hs;
                s2p[nt2*64 + grow] = v;   // [colhalf][row]
            }
        }
    }
    __syncthreads();
    if (t < 64) srow[t] = s2p[t] + s2p[64 + t];
    __syncthreads();

    // ---- segmented sum over sorted batch, one atomic per run ----
    if (t < 64) {
        int node = n0 + t;
        int b = (node < N) ? batch[node] : -1;
        int pb = (t == 0) ? -2 : ((node - 1 < N) ? batch[node - 1] : -1);
        if (b >= 0 && b != pb) {
            float acc = 0.f;
            int j = t;
            while (j < 64 && (n0 + j) < N && batch[n0 + j] == b) { acc += srow[j]; ++j; }
            atomicAdd(&gf1d[b], acc);
        }
    }
}

__global__ void final_sigmoid(const float* __restrict__ gf1d, const float* __restrict__ bout,
                              float* __restrict__ out, int G)
{
    int g = blockIdx.x * 256 + threadIdx.x;
    if (g < G) out[g] = 1.f / (1.f + expf(-(gf1d[g] + bout[0])));
}

extern "C" void kernel_launch(void* const* d_in, const int* in_sizes, int n_in,
                              void* d_out, int out_size, void* d_ws, size_t ws_size,
                              hipStream_t stream)
{
    const float* h    = (const float*)d_in[0];
    const float* x    = (const float*)d_in[1];
    const int*   batch= (const int*)d_in[2];
    const float* W1   = (const float*)d_in[3];
    const float* b1   = (const float*)d_in[4];
    const float* W2   = (const float*)d_in[5];
    const float* b2   = (const float*)d_in[6];
    const float* Wout = (const float*)d_in[7];
    const float* bout = (const float*)d_in[8];
    float* out = (float*)d_out;

    const int N = in_sizes[2];
    const int G = out_size;

    // workspace layout (499,712 B total)
    char* ws = (char*)d_ws;
    float* gf1d = (float*)ws;                                  // 8192 B
    unsigned short* w1h = (unsigned short*)(ws + 8192);        // 212,992 B
    unsigned short* w1l = w1h + (size_t)W1P_SH8 * 8;           // 212,992 B
    unsigned short* w2h = w1l + (size_t)W1P_SH8 * 8;           //  32,768 B
    unsigned short* w2l = w2h + (size_t)W2P_SH8 * 8;           //  32,768 B

    hipMemsetAsync(gf1d, 0, (size_t)G * sizeof(float), stream);
    pack_weights<<<(W1P_SH8 + W2P_SH8 + 255) / 256, 256, 0, stream>>>(W1, W2, w1h, w1l, w2h, w2l);
    fused_readout<<<(N + BM - 1) / BM, 256, 0, stream>>>(h, x, batch, w1h, w1l, w2h, w2l,
                                                         b1, b2, Wout, gf1d, N);
    final_sigmoid<<<(G + 255) / 256, 256, 0, stream>>>(gf1d, bout, out, G);
}

// Round 3
// 221.158 us; speedup vs baseline: 3.5460x; 1.2775x over previous
//
#include <hip/hip_runtime.h>
#include <math.h>

// Fused GNN readout via bf16x2-split MFMA (v_mfma_f32_32x32x16_bf16):
//   feat1 = relu(concat(h,x) @ W1 + b1)      [N,256]   GEMM1: K=400 (pad 416), A/B both hi+lo (3 MFMA)
//   feat2 = relu(feat1 @ W2 + b2)            [N,64]    GEMM2: K=256, A=bf16(feat1) hi only, B hi+lo (2 MFMA)
//   s_n   = feat2 . Wout                      scalar per node
//   out   = sigmoid(segment_sum(s_n) + bout) [G]
// R3: B-fragment register pipeline at 12-MFMA granularity + single-plane F1
//     (LDS 64->32 KiB => 4 blocks/CU).

typedef __attribute__((ext_vector_type(8)))  short short8v;
typedef __attribute__((ext_vector_type(16))) float f32x16;

#define G_NUM 2048
#define HID 200
#define EMB 200
#define DIN 400
#define NH1 256
#define NH2 64
#define BM  64
#define NKS1 26        // bf16 K-steps (of 16) for GEMM1, K padded 400->416
#define NCHUNK 13      // 32-fp32-col staging chunks
#define NKS2 16        // K-steps for GEMM2 (K=256)
#define AKS 40         // A-stage LDS row stride in bf16 (80B: 16B-aligned)

#define W1P_SH8 (NKS1*8*64)   // 13312 fragments (16B each) per plane
#define W2P_SH8 (NKS2*2*64)   // 2048

__device__ __forceinline__ unsigned short f2bf(float f) {
    union { float f; unsigned u; } v; v.f = f;
    unsigned r = v.u + 0x7fffu + ((v.u >> 16) & 1u);   // RNE
    return (unsigned short)(r >> 16);
}
__device__ __forceinline__ float bf2f(unsigned short b) {
    union { unsigned u; float f; } v; v.u = ((unsigned)b) << 16;
    return v.f;
}

// Pre-pack W1/W2 into MFMA-fragment order, hi/lo bf16 planes.
// Fragment (ks, ntile, lane) holds 8 bf16: B[k0+j][col], k0=ks*16+(lane>>5)*8,
// col=ntile*32+(lane&31). Contiguous-8 k in BOTH A and B => any consistent
// hw k-permutation cancels in the dot product.
__global__ void pack_weights(const float* __restrict__ W1, const float* __restrict__ W2,
                             unsigned short* __restrict__ w1h, unsigned short* __restrict__ w1l,
                             unsigned short* __restrict__ w2h, unsigned short* __restrict__ w2l)
{
    int idx = blockIdx.x * 256 + threadIdx.x;
    if (idx < W1P_SH8) {
        int l  = idx & 63;
        int nt = (idx >> 6) & 7;
        int ks = idx >> 9;
        int col = nt * 32 + (l & 31);
        int k0  = ks * 16 + (l >> 5) * 8;
        short8v H, L;
        #pragma unroll
        for (int j = 0; j < 8; ++j) {
            int k = k0 + j;
            float v = (k < DIN) ? W1[(size_t)k * NH1 + col] : 0.f;
            unsigned short hh = f2bf(v);
            H[j] = (short)hh;
            L[j] = (short)f2bf(v - bf2f(hh));
        }
        ((short8v*)w1h)[idx] = H;
        ((short8v*)w1l)[idx] = L;
    } else if (idx < W1P_SH8 + W2P_SH8) {
        int i2 = idx - W1P_SH8;
        int l  = i2 & 63;
        int nt = (i2 >> 6) & 1;
        int ks = i2 >> 7;
        int col = nt * 32 + (l & 31);
        int k0  = ks * 16 + (l >> 5) * 8;
        short8v H, L;
        #pragma unroll
        for (int j = 0; j < 8; ++j) {
            float v = W2[(size_t)(k0 + j) * NH2 + col];
            unsigned short hh = f2bf(v);
            H[j] = (short)hh;
            L[j] = (short)f2bf(v - bf2f(hh));
        }
        ((short8v*)w2h)[i2] = H;
        ((short8v*)w2l)[i2] = L;
    }
}

__launch_bounds__(256, 4)
__global__ void fused_readout(const float* __restrict__ h, const float* __restrict__ x,
                              const int* __restrict__ batch,
                              const unsigned short* __restrict__ w1h, const unsigned short* __restrict__ w1l,
                              const unsigned short* __restrict__ w2h, const unsigned short* __restrict__ w2l,
                              const float* __restrict__ b1, const float* __restrict__ b2,
                              const float* __restrict__ Wout,
                              float* __restrict__ gf1d, int N)
{
    // 32768 B LDS, time-multiplexed:
    //   [GEMM1] Ast: 2 bufs x 2 planes x [64][AKS] bf16 = 20480 B at offset 0
    //   [GEMM2] F1h [64][256] bf16 = 32768 B (XOR-8-block swizzled cols)
    //   [pool ] s2p[2][64] f32 at 0, srow[64] f32 at byte 512
    __shared__ __align__(16) unsigned short lds[16384];
    unsigned short* Ast = lds;
    unsigned short* F1h = lds;
    float* s2p  = (float*)lds;          // 128 floats
    float* srow = (float*)(lds + 256);  // 64 floats (byte 512)

    const int t    = threadIdx.x;
    const int lane = t & 63;
    const int w    = t >> 6;
    const int n0   = blockIdx.x * BM;
    const int l31  = lane & 31;
    const int hs   = lane >> 5;         // k-half select

    // staging mapping: 4 threads per node row, 8 fp32 cols each
    const int  sRow   = t >> 2;
    const int  sK     = (t & 3) * 8;
    const int  gnode  = n0 + sRow;
    const bool rowOk  = (gnode < N);
    const float* hrow = h + (size_t)gnode * HID;
    const float* xrow = x + (size_t)gnode * EMB;

    const short8v* W1H = (const short8v*)w1h;
    const short8v* W1L = (const short8v*)w1l;

    f32x16 acc00, acc01, acc10, acc11;
    #pragma unroll
    for (int r = 0; r < 16; ++r) { acc00[r] = 0.f; acc01[r] = 0.f; acc10[r] = 0.f; acc11[r] = 0.f; }

    // ---- stage chunk 0 (cols 0..31, all from h) ----
    {
        float4 ga = make_float4(0,0,0,0), gb = make_float4(0,0,0,0);
        if (rowOk) { ga = *(const float4*)&hrow[sK]; gb = *(const float4*)&hrow[sK + 4]; }
        float vv[8] = {ga.x,ga.y,ga.z,ga.w,gb.x,gb.y,gb.z,gb.w};
        short8v H, L;
        #pragma unroll
        for (int j = 0; j < 8; ++j) {
            unsigned short hh = f2bf(vv[j]);
            H[j] = (short)hh; L[j] = (short)f2bf(vv[j] - bf2f(hh));
        }
        *(short8v*)&Ast[(0*64 + sRow)*AKS + sK] = H;   // buf0 plane hi
        *(short8v*)&Ast[(1*64 + sRow)*AKS + sK] = L;   // buf0 plane lo
    }

    // B-fragment base index for (chunk c, k-half s): frag = base + nt*64
    #define BBASE(c, s) ((size_t)(((2*(c) + (s)) * 8) + w * 2) * 64 + lane)

    // preload B frags for (c=0, s=0)
    short8v cbh0, cbh1, cbl0, cbl1;
    {
        size_t b0 = BBASE(0, 0);
        cbh0 = W1H[b0]; cbh1 = W1H[b0 + 64];
        cbl0 = W1L[b0]; cbl1 = W1L[b0 + 64];
    }
    __syncthreads();

    // ================= GEMM1 (B pipelined at 12-MFMA granularity) =================
    for (int c = 0; c < NCHUNK; ++c) {
        const int  buf     = c & 1;
        const bool hasNext = (c + 1 < NCHUNK);

        // next-chunk global A loads (issued early, consumed in step 5)
        float4 ga = make_float4(0,0,0,0), gb = make_float4(0,0,0,0);
        if (hasNext && rowOk) {
            int col0 = (c + 1) * 32 + sK;
            if (col0 + 8 <= HID)      { ga = *(const float4*)&hrow[col0];       gb = *(const float4*)&hrow[col0 + 4]; }
            else if (col0 < DIN)      { ga = *(const float4*)&xrow[col0 - HID]; gb = *(const float4*)&xrow[col0 - HID + 4]; }
        }

        #pragma unroll
        for (int s = 0; s < 2; ++s) {
            // prefetch B frags for next s-step (next half-chunk, or next chunk's first)
            short8v nbh0, nbh1, nbl0, nbl1;
            {
                size_t nb = (s == 0) ? BBASE(c, 1)
                                     : BBASE(hasNext ? c + 1 : 0, 0);
                nbh0 = W1H[nb]; nbh1 = W1H[nb + 64];
                nbl0 = W1L[nb]; nbl1 = W1L[nb + 64];
            }
            // A fragments for this s-step (LDS)
            short8v ah0, ah1, al0, al1;
            {
                int offH = (buf*2)*64*AKS + s*16 + hs*8;
                ah0 = *(const short8v*)&Ast[offH + (     l31)*AKS];
                ah1 = *(const short8v*)&Ast[offH + (32 + l31)*AKS];
                al0 = *(const short8v*)&Ast[offH + 64*AKS + (     l31)*AKS];
                al1 = *(const short8v*)&Ast[offH + 64*AKS + (32 + l31)*AKS];
            }
            // 12 MFMAs
            acc00 = __builtin_amdgcn_mfma_f32_32x32x16_bf16(ah0, cbh0, acc00, 0,0,0);
            acc00 = __builtin_amdgcn_mfma_f32_32x32x16_bf16(ah0, cbl0, acc00, 0,0,0);
            acc00 = __builtin_amdgcn_mfma_f32_32x32x16_bf16(al0, cbh0, acc00, 0,0,0);
            acc01 = __builtin_amdgcn_mfma_f32_32x32x16_bf16(ah0, cbh1, acc01, 0,0,0);
            acc01 = __builtin_amdgcn_mfma_f32_32x32x16_bf16(ah0, cbl1, acc01, 0,0,0);
            acc01 = __builtin_amdgcn_mfma_f32_32x32x16_bf16(al0, cbh1, acc01, 0,0,0);
            acc10 = __builtin_amdgcn_mfma_f32_32x32x16_bf16(ah1, cbh0, acc10, 0,0,0);
            acc10 = __builtin_amdgcn_mfma_f32_32x32x16_bf16(ah1, cbl0, acc10, 0,0,0);
            acc10 = __builtin_amdgcn_mfma_f32_32x32x16_bf16(al1, cbh0, acc10, 0,0,0);
            acc11 = __builtin_amdgcn_mfma_f32_32x32x16_bf16(ah1, cbh1, acc11, 0,0,0);
            acc11 = __builtin_amdgcn_mfma_f32_32x32x16_bf16(ah1, cbl1, acc11, 0,0,0);
            acc11 = __builtin_amdgcn_mfma_f32_32x32x16_bf16(al1, cbh1, acc11, 0,0,0);
            cbh0 = nbh0; cbh1 = nbh1; cbl0 = nbl0; cbl1 = nbl1;
        }

        // convert + stage next A chunk into the other buffer
        if (hasNext) {
            float vv[8] = {ga.x,ga.y,ga.z,ga.w,gb.x,gb.y,gb.z,gb.w};
            short8v H, L;
            #pragma unroll
            for (int j = 0; j < 8; ++j) {
                unsigned short hh = f2bf(vv[j]);
                H[j] = (short)hh; L[j] = (short)f2bf(vv[j] - bf2f(hh));
            }
            int nb = buf ^ 1;
            *(short8v*)&Ast[((nb*2 + 0)*64 + sRow)*AKS + sK] = H;
            *(short8v*)&Ast[((nb*2 + 1)*64 + sRow)*AKS + sK] = L;
        }
        __syncthreads();
    }
    #undef BBASE

    // ---- epilogue1: bias + relu + bf16 (hi only) -> F1h (XOR-swizzled) ----
    // C/D layout: col = lane&31, row = (r&3) + 8*(r>>2) + 4*(lane>>5)
    const float b1c0 = b1[w*64 + l31];
    const float b1c1 = b1[w*64 + 32 + l31];
#define EPI1(ACC, MI, NI) do {                                            \
        int gcol = w*64 + (NI)*32 + l31;                                  \
        float bb = (NI) ? b1c1 : b1c0;                                    \
        _Pragma("unroll")                                                 \
        for (int r = 0; r < 16; ++r) {                                    \
            int grow = (MI)*32 + (r & 3) + 8*(r >> 2) + 4*hs;             \
            float v = fmaxf(ACC[r] + bb, 0.f);                            \
            int phys = grow*256 + (((gcol >> 3) ^ (grow & 31)) << 3) + (gcol & 7); \
            F1h[phys] = f2bf(v);                                          \
        } } while (0)
    EPI1(acc00, 0, 0); EPI1(acc01, 0, 1); EPI1(acc10, 1, 0); EPI1(acc11, 1, 1);
#undef EPI1
    __syncthreads();

    // ================= GEMM2: feat2 = relu(feat1 @ W2 + b2) =================
    // A = bf16(feat1) hi-only; B = W2 hi+lo (2 MFMAs per K-step).
    f32x16 acc2;
    #pragma unroll
    for (int r = 0; r < 16; ++r) acc2[r] = 0.f;
    const int m2   = w >> 1;      // node-row half
    const int nt2  = w & 1;       // col half
    const int arow = m2*32 + l31;

    const short8v* W2H = (const short8v*)w2h;
    const short8v* W2L = (const short8v*)w2l;
    short8v bhc = W2H[(size_t)nt2*64 + lane];
    short8v blc = W2L[(size_t)nt2*64 + lane];
    #pragma unroll
    for (int ks = 0; ks < NKS2; ++ks) {
        short8v bhn = bhc, bln = blc;
        if (ks + 1 < NKS2) {
            size_t nbase = (size_t)((ks + 1)*2 + nt2)*64 + lane;
            bhn = W2H[nbase];
            bln = W2L[nbase];
        }
        int blk  = (ks*2 + hs) ^ (arow & 31);
        short8v ah2 = *(const short8v*)&F1h[arow*256 + blk*8];
        acc2 = __builtin_amdgcn_mfma_f32_32x32x16_bf16(ah2, bhc, acc2, 0,0,0);
        acc2 = __builtin_amdgcn_mfma_f32_32x32x16_bf16(ah2, blc, acc2, 0,0,0);
        bhc = bhn; blc = bln;
    }
    __syncthreads();   // all F1 reads done; s2p/srow may now overwrite LDS

    // ---- epilogue2: s_n = relu(feat2 + b2) . Wout, 32-col shfl reduce ----
    {
        const int   col2 = nt2*32 + l31;
        const float b2c  = b2[col2];
        const float woc  = Wout[col2];
        #pragma unroll
        for (int r = 0; r < 16; ++r) {
            float v = fmaxf(acc2[r] + b2c, 0.f) * woc;
            v += __shfl_xor(v, 1);
            v += __shfl_xor(v, 2);
            v += __shfl_xor(v, 4);
            v += __shfl_xor(v, 8);
            v += __shfl_xor(v, 16);
            if (l31 == 0) {
                int grow = m2*32 + (r & 3) + 8*(r >> 2) + 4*hs;
                s2p[nt2*64 + grow] = v;   // [colhalf][row]
            }
        }
    }
    __syncthreads();
    if (t < 64) srow[t] = s2p[t] + s2p[64 + t];
    __syncthreads();

    // ---- segmented sum over sorted batch, one atomic per run ----
    if (t < 64) {
        int node = n0 + t;
        int b = (node < N) ? batch[node] : -1;
        int pb = (t == 0) ? -2 : ((node - 1 < N) ? batch[node - 1] : -1);
        if (b >= 0 && b != pb) {
            float acc = 0.f;
            int j = t;
            while (j < 64 && (n0 + j) < N && batch[n0 + j] == b) { acc += srow[j]; ++j; }
            atomicAdd(&gf1d[b], acc);
        }
    }
}

__global__ void final_sigmoid(const float* __restrict__ gf1d, const float* __restrict__ bout,
                              float* __restrict__ out, int G)
{
    int g = blockIdx.x * 256 + threadIdx.x;
    if (g < G) out[g] = 1.f / (1.f + expf(-(gf1d[g] + bout[0])));
}

extern "C" void kernel_launch(void* const* d_in, const int* in_sizes, int n_in,
                              void* d_out, int out_size, void* d_ws, size_t ws_size,
                              hipStream_t stream)
{
    const float* h    = (const float*)d_in[0];
    const float* x    = (const float*)d_in[1];
    const int*   batch= (const int*)d_in[2];
    const float* W1   = (const float*)d_in[3];
    const float* b1   = (const float*)d_in[4];
    const float* W2   = (const float*)d_in[5];
    const float* b2   = (const float*)d_in[6];
    const float* Wout = (const float*)d_in[7];
    const float* bout = (const float*)d_in[8];
    float* out = (float*)d_out;

    const int N = in_sizes[2];
    const int G = out_size;

    // workspace layout (499,712 B total)
    char* ws = (char*)d_ws;
    float* gf1d = (float*)ws;                                  // 8192 B
    unsigned short* w1h = (unsigned short*)(ws + 8192);        // 212,992 B
    unsigned short* w1l = w1h + (size_t)W1P_SH8 * 8;           // 212,992 B
    unsigned short* w2h = w1l + (size_t)W1P_SH8 * 8;           //  32,768 B
    unsigned short* w2l = w2h + (size_t)W2P_SH8 * 8;           //  32,768 B

    hipMemsetAsync(gf1d, 0, (size_t)G * sizeof(float), stream);
    pack_weights<<<(W1P_SH8 + W2P_SH8 + 255) / 256, 256, 0, stream>>>(W1, W2, w1h, w1l, w2h, w2l);
    fused_readout<<<(N + BM - 1) / BM, 256, 0, stream>>>(h, x, batch, w1h, w1l, w2h, w2l,
                                                         b1, b2, Wout, gf1d, N);
    final_sigmoid<<<(G + 255) / 256, 256, 0, stream>>>(gf1d, bout, out, G);
}